// Round 16
// baseline (496.765 us; speedup 1.0000x reference)
//
#include <hip/hip_runtime.h>
#include <hip/hip_bf16.h>

#define NN 768
#define NE 24576
#define NPOS 4096
#define NCELL (NN*NN)   // 589824
#define NBLK 2304
#define NBIG 4608       // k_big: 128 cells/block, 2 threads/cell, 256 threads
#define BCELLS 128
#define CAP 4
#define NREP 16

typedef __hip_bfloat16 bf16;

__device__ __forceinline__ float ldf(const void* p, int i, int mode) {
    return mode ? __bfloat162float(((const bf16*)p)[i]) : ((const float*)p)[i];
}
__device__ __forceinline__ float aread(float* p) { return atomicAdd(p, 0.f); }
__device__ __forceinline__ int areadi(int* p) { return atomicAdd(p, 0); }

template<int D, int HALF>
__device__ __forceinline__ void redRound(float* v, int lane) {
#pragma unroll
    for (int i = 0; i < HALF; i++) {
        float snd = (lane & D) ? v[i] : v[i + HALF];
        float r = __shfl_xor(snd, D);
        v[i] = ((lane & D) ? v[i + HALF] : v[i]) + r;
    }
}

#define DOT4(Z, A, W) Z += A.x * W.x + A.y * W.y + A.z * W.z + A.w * W.w

// bf16 unpack helpers: uint = (bf16 even) | (bf16 odd << 16)
#define BLO(u) __uint_as_float((u) << 16)
#define BHI(u) __uint_as_float((u) & 0xFFFF0000u)

// half-row accumulate: 16 bf16 products (2 uint4 per side) into q0..q3
#define ACCUM16(xA,xB, mA,mB, q0,q1,q2,q3) { \
    q0.x += BLO(xA.x)*BLO(mA.x); q0.y += BHI(xA.x)*BHI(mA.x); \
    q0.z += BLO(xA.y)*BLO(mA.y); q0.w += BHI(xA.y)*BHI(mA.y); \
    q1.x += BLO(xA.z)*BLO(mA.z); q1.y += BHI(xA.z)*BHI(mA.z); \
    q1.z += BLO(xA.w)*BLO(mA.w); q1.w += BHI(xA.w)*BHI(mA.w); \
    q2.x += BLO(xB.x)*BLO(mB.x); q2.y += BHI(xB.x)*BHI(mB.x); \
    q2.z += BLO(xB.y)*BLO(mB.y); q2.w += BHI(xB.y)*BHI(mB.y); \
    q3.x += BLO(xB.z)*BLO(mB.z); q3.y += BHI(xB.z)*BHI(mB.z); \
    q3.z += BLO(xB.w)*BLO(mB.w); q3.w += BHI(xB.w)*BHI(mB.w); }

// ---------------- edge scatter (b<96) || weight conv (b==96); last scatter block: row scan + dinv ----------------
__global__ void k_scatter(const int* __restrict__ ei, int* __restrict__ cell, int* __restrict__ rowlen,
                          int* __restrict__ row_ptr, float* __restrict__ dinv, int* __restrict__ dc,
                          const void* __restrict__ gW, const void* __restrict__ gB,
                          const void* __restrict__ m1W, const void* __restrict__ m1B,
                          const void* __restrict__ m2W, const void* __restrict__ m2B,
                          const void* __restrict__ m3W, const void* __restrict__ m3B,
                          const void* __restrict__ lW,  const void* __restrict__ lB,
                          const void* __restrict__ emb, int* __restrict__ modeg,
                          float* __restrict__ gwf, float* __restrict__ gbf,
                          float* __restrict__ w1f, float* __restrict__ b1f,
                          float* __restrict__ w2f, float* __restrict__ b2f,
                          float* __restrict__ w3q, float* __restrict__ linf, float* __restrict__ linb) {
    int t = threadIdx.x;
    if (blockIdx.x == 96) {
        __shared__ int bad;
        if (t == 0) bad = 0;
        __syncthreads();
        int local = 0;
        for (int i = t; i < 3232; i += 256) {
            float a = fabsf(__bfloat162float(((const bf16*)emb)[i]));
            if (!(a < 100.f)) local = 1;
        }
        if (local) atomicOr(&bad, 1);
        __syncthreads();
        int mode = bad ? 0 : 1;
        if (t == 0) *modeg = mode;
        for (int i = t; i < 2048; i += 256) {
            gwf[i] = ldf(gW, i, mode);
            w1f[i] = ldf(m1W, i, mode);
            w2f[i] = ldf(m2W, i, mode);
        }
        for (int i = t; i < 64; i += 256) { gbf[i] = ldf(gB, i, mode); linf[i] = ldf(lW, i, mode); }
        if (t < 32) { b1f[t] = ldf(m1B, t, mode); b2f[t] = ldf(m2B, t, mode); }
        // w3q row d (stride 36 floats, 16B-aligned): [W3[0..31][d], ind, b3, 0, 0]
        for (int i = t; i < 1056; i += 256) { int c = i >> 5, d = i & 31; w3q[d * 36 + c] = ldf(m3W, i, mode); }
        if (t < 32) { w3q[t * 36 + 33] = ldf(m3B, t, mode); w3q[t * 36 + 34] = 0.f; w3q[t * 36 + 35] = 0.f; }
        if (t == 0) linb[0] = ldf(lB, 0, mode);
        return;
    }
    __shared__ int amlast;
    __shared__ int sI[256];
    int e = blockIdx.x * 256 + t;
    int a = ei[e], b = ei[NE + e];
    if ((unsigned)a < (unsigned)NN && (unsigned)b < (unsigned)NN) {
        int old = atomicAdd(&cell[a * NN + b], 1);
        if (old == 0) atomicAdd(&rowlen[a], 1);
    }
    __syncthreads();
    if (t == 0) { __threadfence(); amlast = (atomicAdd(dc, 1) == 95) ? 1 : 0; }
    __syncthreads();
    if (!amlast) return;
    int i0 = 3 * t;
    int r0 = areadi(&rowlen[i0]), r1 = areadi(&rowlen[i0 + 1]), r2 = areadi(&rowlen[i0 + 2]);
    dinv[i0]     = rsqrtf((float)r0 + 1.f);
    dinv[i0 + 1] = rsqrtf((float)r1 + 1.f);
    dinv[i0 + 2] = rsqrtf((float)r2 + 1.f);
    int s3 = r0 + r1 + r2;
    sI[t] = s3;
    __syncthreads();
    for (int off = 1; off < 256; off <<= 1) {
        int tmp = (t >= off) ? sI[t - off] : 0;
        __syncthreads();
        sI[t] += tmp;
        __syncthreads();
    }
    int excl = sI[t] - s3;
    row_ptr[i0] = excl;
    row_ptr[i0 + 1] = excl + r0;
    row_ptr[i0 + 2] = excl + r0 + r1;
    if (t == 255) row_ptr[NN] = sI[255];
}

// ---------------- CSR fill + rtot (b<2304) || emb gather E -> bufA (b>=2304) ----------------
__global__ void k_fill(int* __restrict__ cell, const int* __restrict__ row_ptr, int* __restrict__ cursor,
                       int* __restrict__ col_idx, float* __restrict__ cntv, int* __restrict__ pr_row,
                       const int* __restrict__ rowlen, int* __restrict__ rtot,
                       const int* __restrict__ x, const void* __restrict__ emb,
                       const int* __restrict__ modep, float* __restrict__ bufA) {
    int t = threadIdx.x;
    int b = blockIdx.x;
    if (b < NBLK) {
        int idx = b * 256 + t;
        int i = idx / NN;
        int j = idx - i * NN;
        int cv = cell[idx];
        if (cv > 0) {
            int p = row_ptr[i] + atomicAdd(&cursor[i], 1);
            col_idx[p] = j; cntv[p] = (float)cv; pr_row[p] = i;
            cell[idx] = p;
            atomicAdd(&rtot[i], rowlen[j]);
        } else cell[idx] = -1;
    } else {
        int idx = (b - NBLK) * 256 + t;   // 768*32
        int i = idx >> 5, k = idx & 31;
        int xi = x[i]; if (xi < 0) xi = 0; if (xi > 100) xi = 100;
        bufA[idx] = ldf(emb, xi * 32 + k, *modep);
    }
}

// ---------------- b==0: row_base scan || b>=1: ROW-PER-BLOCK agg(E) then @W0 -> bufB ----------------
__global__ void k_aggmw0(const int* __restrict__ rtot, int* __restrict__ row_base,
                         const int* __restrict__ row_ptr, const int* __restrict__ col_idx,
                         const float* __restrict__ bufA, const float* __restrict__ dinv,
                         const float* __restrict__ gwf, const float* __restrict__ gbf,
                         float* __restrict__ bufB) {
    int t = threadIdx.x;
    if (blockIdx.x == 0) {
        __shared__ int sI[256];
        int r3[3]; int s3 = 0;
#pragma unroll
        for (int q = 0; q < 3; q++) { r3[q] = rtot[3 * t + q]; s3 += r3[q]; }
        sI[t] = s3;
        __syncthreads();
        for (int off = 1; off < 256; off <<= 1) {
            int tmp = (t >= off) ? sI[t - off] : 0;
            __syncthreads();
            sI[t] += tmp;
            __syncthreads();
        }
        int run = sI[t] - s3;
        row_base[3 * t] = run;
        row_base[3 * t + 1] = run + r3[0];
        row_base[3 * t + 2] = run + r3[0] + r3[1];
        return;
    }
    __shared__ float sg8[8][32];
    __shared__ float agg[32];
    int sgi = t >> 5, k = t & 31;
    int i = blockIdx.x - 1;
    int base = row_ptr[i], len = row_ptr[i + 1] - base;
    float di = dinv[i];
    float acc = (sgi == 0) ? di * bufA[i * 32 + k] : 0.f;
    for (int e = sgi; e < len; e += 8) {
        int c = col_idx[base + e];
        acc += dinv[c] * bufA[c * 32 + k];
    }
    sg8[sgi][k] = acc;
    __syncthreads();
    if (t < 32) {
        float s = 0.f;
#pragma unroll
        for (int q = 0; q < 8; q++) s += sg8[q][k];
        agg[k] = di * s;
    }
    __syncthreads();
    if (t < 32) {
        int d = k;
        float s = gbf[d];
#pragma unroll
        for (int kk = 0; kk < 32; kk++) s += agg[kk] * gwf[kk * 32 + d];
        bufB[i * 32 + d] = s;
    }
}

// ---------------- FUSED: per-row path histogram + aggmw1 (768 blocks) ----------------
__global__ void k_hist(const int* __restrict__ row_ptr, const int* __restrict__ col_idx,
                       const int* __restrict__ row_base,
                       int* __restrict__ pcur, int2* __restrict__ paths2, int cap,
                       const float* __restrict__ bufB, const float* __restrict__ dinv,
                       const float* __restrict__ gwf, const float* __restrict__ gbf,
                       float* __restrict__ bufA, float* __restrict__ stats1) {
    __shared__ float r1[256], r2[256];
    __shared__ float nmean[32], nrstd[32];
    __shared__ int hist[NN];
    __shared__ int sc[256];
    __shared__ float sg8[8][32];
    __shared__ float agg[32];
    int t = threadIdx.x;
    int i = blockIdx.x;

    // ---- phase 0: local nrm0 from bufB (redundant per block; bufB is L2-resident) ----
    {
        int dd = t & 31, g = t >> 5;
        float s = 0.f, s2 = 0.f;
        for (int r = g; r < NN; r += 8) { float v = bufB[r * 32 + dd]; s += v; s2 += v * v; }
        r1[t] = s; r2[t] = s2;
        __syncthreads();
        if (t < 32) {
            float a = 0.f, b2 = 0.f;
            for (int k = 0; k < 8; k++) { a += r1[k * 32 + t]; b2 += r2[k * 32 + t]; }
            float mean = a / (float)NN;
            float var = b2 / (float)NN - mean * mean;
            nmean[t] = mean;
            nrstd[t] = rsqrtf(fmaxf(var, 0.f) + 1e-5f);
        }
    }

    int base = row_ptr[i], len = row_ptr[i + 1] - base;
    int rb = row_base[i];
    int wave = t >> 6, lane = t & 63;
    int sub = lane >> 5, l2 = lane & 31;
    for (int j = t; j < NN; j += 256) hist[j] = 0;
    __syncthreads();

    // ---- phase 1: histogram ----
    for (int ee = wave * 2 + sub; ee < len; ee += 8) {
        int k = col_idx[base + ee];
        int kb = row_ptr[k], ke = row_ptr[k + 1];
        for (int e = kb + l2; e < ke; e += 32) atomicAdd(&hist[col_idx[e]], 1);
    }
    __syncthreads();
    int h0 = hist[3 * t], h1 = hist[3 * t + 1], h2 = hist[3 * t + 2];
    int s3 = h0 + h1 + h2;
    sc[t] = s3;
    __syncthreads();
    for (int off = 1; off < 256; off <<= 1) {
        int tmp = (t >= off) ? sc[t - off] : 0;
        __syncthreads();
        sc[t] += tmp;
        __syncthreads();
    }
    int excl = sc[t] - s3;
    int n0 = i * NN + 3 * t;
    pcur[n0]     = rb + excl + h0;            // absolute END offsets
    pcur[n0 + 1] = rb + excl + h0 + h1;
    pcur[n0 + 2] = rb + excl + h0 + h1 + h2;
    hist[3 * t] = excl;
    hist[3 * t + 1] = excl + h0;
    hist[3 * t + 2] = excl + h0 + h1;
    __syncthreads();

    // ---- phase 2: fill path records ----
    for (int ee = wave * 2 + sub; ee < len; ee += 8) {
        int e1 = base + ee;
        int k = col_idx[e1];
        int kb = row_ptr[k], ke = row_ptr[k + 1];
        for (int e = kb + l2; e < ke; e += 32) {
            int j = col_idx[e];
            int slot = rb + atomicAdd(&hist[j], 1);
            if (slot < cap) {
                // pack cell id n (20 bits) into high bits: x[31:15]=n[16:0], y[17:15]=n[19:17]
                unsigned n2 = (unsigned)(i * NN + j);
                paths2[slot] = make_int2((int)((unsigned)e1 | ((n2 & 0x1FFFFu) << 15)),
                                         (int)((unsigned)e  | ((n2 >> 17) << 15)));
            }
        }
    }
    __syncthreads();

    // ---- phase 3: aggmw1 for row i (uses local nmean/nrstd) ----
    {
        int sgi = t >> 5, k = t & 31;
        float mk = nmean[k], rk = nrstd[k];
        float di = dinv[i];
        float acc = (sgi == 0) ? di * fmaxf((bufB[i * 32 + k] - mk) * rk, 0.f) : 0.f;
        for (int e = sgi; e < len; e += 8) {
            int c = col_idx[base + e];
            acc += dinv[c] * fmaxf((bufB[c * 32 + k] - mk) * rk, 0.f);
        }
        sg8[sgi][k] = acc;
        __syncthreads();
        if (t < 32) {
            float s = 0.f;
#pragma unroll
            for (int q = 0; q < 8; q++) s += sg8[q][k];
            agg[k] = di * s;
        }
        __syncthreads();
        if (t < 32) {
            int d = k;
            const float* W = gwf + 1024;
            float s = gbf[32 + d];
#pragma unroll
            for (int kk = 0; kk < 32; kk++) s += agg[kk] * W[kk * 32 + d];
            bufA[i * 32 + d] = s;
            float* rep = stats1 + (blockIdx.x & (NREP - 1)) * 80;
            atomicAdd(&rep[d], s);
            atomicAdd(&rep[32 + d], s * s);
        }
    }
}

// ---------------- edge MLP (b<3072) || h write (b>=3072); nrm1 computed locally; xep/mulp bf16 ----------------
__global__ void k_emlp(const float* __restrict__ bufA, const float* __restrict__ stats1,
                       const int* __restrict__ row_ptr, const int* __restrict__ col_idx,
                       const int* __restrict__ pr_row, const float* __restrict__ cntv,
                       const float* __restrict__ w1f, const float* __restrict__ b1f,
                       const float* __restrict__ w2f, const float* __restrict__ b2f,
                       bf16* __restrict__ xepb, bf16* __restrict__ mulpb, float* __restrict__ h) {
    __shared__ float nmean[32], nrstd[32];
    int t = threadIdx.x;
    int b = blockIdx.x;
    if (t < 32) {
        float s = 0.f, s2 = 0.f;
#pragma unroll
        for (int r = 0; r < NREP; r++) { s += stats1[r * 80 + t]; s2 += stats1[r * 80 + 32 + t]; }
        float mean = s / (float)NN;
        float var = s2 / (float)NN - mean * mean;
        nmean[t] = mean;
        nrstd[t] = rsqrtf(fmaxf(var, 0.f) + 1e-5f);
    }
    __syncthreads();
    if (b < 3072) {
        int d = t & 31;
        int p = b * 8 + (t >> 5);
        if (p >= row_ptr[NN]) {
            if (p < NE) { xepb[p * 32 + d] = __float2bfloat16(0.f); mulpb[p * 32 + d] = __float2bfloat16(0.f); }
            return;
        }
        int i = pr_row[p], j = col_idx[p];
        float a1 = b1f[d], a2 = b2f[d];
#pragma unroll
        for (int c = 0; c < 32; c++) {
            float hv = fmaxf((bufA[i * 32 + c] - nmean[c]) * nrstd[c], 0.f);
            a1 += hv * w1f[c * 32 + d];
            a2 += hv * w2f[c * 32 + d];
        }
#pragma unroll
        for (int c = 0; c < 32; c++) {
            float hv = fmaxf((bufA[j * 32 + c] - nmean[c]) * nrstd[c], 0.f);
            a1 += hv * w1f[(32 + c) * 32 + d];
            a2 += hv * w2f[(32 + c) * 32 + d];
        }
        float cv = cntv[p];
        xepb[p * 32 + d]  = __float2bfloat16(cv * fmaxf(a1, 0.f));
        mulpb[p * 32 + d] = __float2bfloat16(cv * fmaxf(a2, 0.f));
    } else {
        int idx = (b - 3072) * 256 + t;
        int d = idx & 31;
        h[idx] = fmaxf((bufA[idx] - nmean[d]) * nrstd[d], 0.f);
    }
}

// ---------------- fused big v16: 2 threads/cell -- halve the accumulator to unlock occupancy ----------------
// The 32-float accumulator is what forced every launch_bounds >4 to spill. Split it: thread pair
// (2t,2t+1) shares a cell, each owning 16 dims (q0..q3). Live set ~halves -> fits the 64-reg
// budget of (256,8) spill-free -> 8 blocks/CU (2x residency) against the ~200cy gather chains.
// Gathers per thread halve (2 uint4/side/path; pair halves read adjacent 16B = coalesced).
// Stage 2: partial z over own 16 dims + shfl_xor(za,1); bias/stats gated to half 0.
__global__ __launch_bounds__(256, 8) void k_big(const int* __restrict__ pcur,
                                                const int2* __restrict__ paths2,
                                                const int* __restrict__ cellA,
                                                const bf16* __restrict__ xepb, const bf16* __restrict__ mulpb,
                                                const float* __restrict__ w3q,
                                                float* __restrict__ stats, int* __restrict__ done,
                                                float* __restrict__ nrm, int cap) {
    __shared__ float qbuf[64 * 32];
    __shared__ int qps[64], qpe[64];
    __shared__ int qsl[BCELLS];
    __shared__ float sS1[32], sS2[32];
    __shared__ float sCm;
    __shared__ int amlast;
    __shared__ int qcnt;
    const uint4* xep4b = (const uint4*)xepb;
    const uint4* mulp4b = (const uint4*)mulpb;
    int t = threadIdx.x;
    int b = blockIdx.x;
    int cell0 = b * BCELLS;
    int lane = t & 63;
    int cl = t >> 1;        // cell-local 0..127
    int ph = t & 1;         // pair half: dims [ph*16, ph*16+16)

    if (t == 0) { sCm = 0.f; qcnt = 0; }
    if (t < 32) { sS1[t] = 0.f; sS2[t] = 0.f; }
    if (t < BCELLS) qsl[t] = -1;
    // per-pair cell meta (adjacent threads load same addr -> broadcast)
    int myn = cell0 + cl;
    int mp1 = pcur[myn];
    int mp0 = (myn == 0) ? 0 : pcur[myn - 1];
    int madj = cellA[myn];
    if (mp0 > cap) mp0 = cap;
    if (mp1 > cap) mp1 = cap;
    __syncthreads();   // qcnt/qsl init visible

    // ---- stage 1a: half-row register gather; all recs prefetched; capped at CAP paths ----
    int len = mp1 - mp0;
    int take = (len > CAP) ? CAP : len;
    if (len > CAP && ph == 0) {
        int s = atomicAdd(&qcnt, 1);
        if (s < 64) { qsl[cl] = s; qps[s] = mp0 + CAP; qpe[s] = mp1; }
    }
    int pm = cap - 1; if (pm < 0) pm = 0;
    int i0 = mp0, i1 = mp0 + 1, i2 = mp0 + 2, i3 = mp0 + 3;
    if (i0 > pm) i0 = pm; if (i1 > pm) i1 = pm; if (i2 > pm) i2 = pm; if (i3 > pm) i3 = pm;
    int2 r0 = paths2[i0];
    int2 r1 = paths2[i1];
    int2 r2 = paths2[i2];
    int2 r3 = paths2[i3];
    float4 q0 = {0.f,0.f,0.f,0.f}, q1 = q0, q2 = q0, q3 = q0;
#pragma unroll
    for (int pp = 0; pp < CAP; pp++) {
        int2 rr = (pp == 0) ? r0 : (pp == 1) ? r1 : (pp == 2) ? r2 : r3;
        if (take > pp) {
            int e1 = rr.x & 0x7FFF;
            int e2 = rr.y & 0x7FFF;
            const uint4* mr = mulp4b + e2 * 4 + ph * 2;
            uint4 mA = mr[0], mB = mr[1];
            const uint4* xr = xep4b + e1 * 4 + ph * 2;
            uint4 xA = xr[0], xB = xr[1];
            ACCUM16(xA, xB, mA, mB, q0, q1, q2, q3);
        }
    }
    __syncthreads();   // queue pushes + qsl visible

    // ---- stage 1b: heavy-cell remainders, wave-parallel (full 32-d lanes, global gathers) ----
    int nq = qcnt; if (nq > 64) nq = 64;
    {
        int wid = t >> 6, h32 = lane >> 5, d = lane & 31;
        for (int e = wid; e < nq; e += 4) {
            int pe = qpe[e];
            float acc = 0.f;
            for (int q = qps[e] + h32; q < pe; q += 2) {
                int2 r = paths2[q];
                acc += __bfloat162float(xepb[(int)((unsigned)r.x & 0x7FFFu) * 32 + d]) *
                       __bfloat162float(mulpb[(int)((unsigned)r.y & 0x7FFFu) * 32 + d]);
            }
            acc += __shfl_xor(acc, 32);
            if (lane < 32) qbuf[e * 32 + lane] = acc;
        }
    }
    __syncthreads();
    {
        int myq = qsl[cl];
        if (myq >= 0) {   // merge own half of the remainder (rare)
            const float4* qb = (const float4*)(qbuf + myq * 32 + ph * 16);
            float4 a0 = qb[0], a1 = qb[1], a2 = qb[2], a3 = qb[3];
            q0.x += a0.x; q0.y += a0.y; q0.z += a0.z; q0.w += a0.w;
            q1.x += a1.x; q1.y += a1.y; q1.z += a1.z; q1.w += a1.w;
            q2.x += a2.x; q2.y += a2.y; q2.z += a2.z; q2.w += a2.w;
            q3.x += a3.x; q3.y += a3.y; q3.z += a3.z; q3.w += a3.w;
        }
    }

    // ---- stage 2: pair computes z per output dim; bias+stats gated to half 0 ----
    float af = (madj >= 0) ? 1.f : 0.f;
    float msk = (len > 0 || madj >= 0) ? 1.f : 0.f;
    float mske = ph ? 0.f : msk;
#pragma unroll
    for (int ch = 0; ch < 2; ch++) {
        float v[32];
#pragma unroll
        for (int j = 0; j < 16; j++) {
            int dd = ch * 16 + j;
            const float4* wr = (const float4*)(w3q + dd * 36);
            float4 wv = wr[8];
            float za = ph ? 0.f : (wv.y + af * wv.x);
            float4 w0 = wr[ph * 4 + 0], w1 = wr[ph * 4 + 1];
            float4 w2 = wr[ph * 4 + 2], w3v = wr[ph * 4 + 3];
            DOT4(za, q0, w0);
            DOT4(za, q1, w1);
            DOT4(za, q2, w2);
            DOT4(za, q3, w3v);
            za += __shfl_xor(za, 1);    // combine pair halves -> full z in both
            v[j] = mske * za;
            v[16 + j] = mske * za * za;
        }
#pragma unroll
        for (int i2r = 0; i2r < 32; i2r++) v[i2r] += __shfl_xor(v[i2r], 32);
        redRound<16, 16>(v, lane);
        redRound<8, 8>(v, lane);
        redRound<4, 4>(v, lane);
        redRound<2, 2>(v, lane);
        redRound<1, 1>(v, lane);
        if (lane < 32) {
            if (lane < 16) atomicAdd(&sS1[ch * 16 + lane], v[0]);
            else           atomicAdd(&sS2[ch * 16 + lane - 16], v[0]);
        }
    }
    {
        float cm2 = mske;
        for (int off = 32; off >= 1; off >>= 1) cm2 += __shfl_xor(cm2, off);
        if (lane == 0) atomicAdd(&sCm, cm2);
    }
    __syncthreads();
    float* srep = stats + (b & (NREP - 1)) * 80;
    if (t < 32) {
        atomicAdd(&srep[t], sS1[t]);
        atomicAdd(&srep[32 + t], sS2[t]);
    }
    if (t == 32) atomicAdd(&srep[64], sCm);
    __syncthreads();
    if (t == 0) {
        __threadfence();
        amlast = (atomicAdd(done, 1) == NBIG - 1) ? 1 : 0;
    }
    __syncthreads();
    if (amlast && t < 32) {
        float sum1 = 0.f, sum2 = 0.f;
        for (int r = 0; r < NREP; r++) {
            sum1 += aread(&stats[r * 80 + t]);
            sum2 += aread(&stats[r * 80 + 32 + t]);
        }
        float cmt = 0.f;
        for (int r = 0; r < NREP; r++) cmt += aread(&stats[r * 80 + 64]);
        if (cmt < 1.f) cmt = 1.f;
        float mean = sum1 / cmt;
        float var = sum2 / cmt - mean * mean;
        nrm[t] = mean;
        nrm[32 + t] = rsqrtf(fmaxf(var, 0.f) + 1e-5f);
    }
}

// ---------------- output: C at pos pairs via path lists, norm, sym, linear (bf16 gathers) ----------------
__global__ void k_out(const int* __restrict__ pos, const int* __restrict__ pcur,
                      const int2* __restrict__ paths2,
                      const int* __restrict__ cell,
                      const bf16* __restrict__ xepb, const bf16* __restrict__ mulpb,
                      const float* __restrict__ h,
                      const float* __restrict__ w3q,
                      const float* __restrict__ nrm,
                      const float* __restrict__ linf, const float* __restrict__ linb,
                      const int* __restrict__ modep, int cap, void* __restrict__ outp) {
    __shared__ float Cb[4][2][32];
    int t = threadIdx.x;
    int w = t >> 6, lane = t & 63, d = lane & 31, dir = lane >> 5;
    int p = blockIdx.x * 4 + w;
    int a = pos[2 * p], b = pos[2 * p + 1];
    if ((unsigned)a >= (unsigned)NN) a = 0;
    if ((unsigned)b >= (unsigned)NN) b = 0;
    int r = dir ? b : a;
    int cc = dir ? a : b;
    int n = r * NN + cc;
    int p1 = pcur[n];
    int p0 = (n == 0) ? 0 : pcur[n - 1];
    if (p0 > cap) p0 = cap; if (p1 > cap) p1 = cap;
    float acc = 0.f;
    for (int q = p0; q < p1; q++) {
        int2 rec = paths2[q];
        int e1 = (int)((unsigned)rec.x & 0x7FFFu);
        int e2 = (int)((unsigned)rec.y & 0x7FFFu);
        acc += __bfloat162float(xepb[e1 * 32 + d]) * __bfloat162float(mulpb[e2 * 32 + d]);
    }
    Cb[w][dir][d] = acc;
    bool adj = cell[n] >= 0;
    float msk = (p1 > p0 || adj) ? 1.f : 0.f;
    __syncthreads();
    float z = w3q[d * 36 + 33] + (adj ? 1.f : 0.f) * w3q[d * 36 + 32];
#pragma unroll
    for (int c = 0; c < 32; c++) z += Cb[w][dir][c] * w3q[d * 36 + c];
    float zn = fmaxf((z - nrm[d]) * nrm[32 + d], 0.f);
    float zp = __shfl_xor(zn, 32);
    float symd = msk * zn * zp;
    float xxd = h[a * 32 + d] * h[b * 32 + d];
    float contrib = symd * linf[d] + xxd * linf[32 + d];
    for (int off = 16; off >= 1; off >>= 1) contrib += __shfl_xor(contrib, off);
    if (lane == 0) {
        float v = contrib + linb[0];
        v = fminf(fmaxf(v, -1e4f), 1e4f);
        if (*modep) ((bf16*)outp)[p] = __float2bfloat16(v);
        else        ((float*)outp)[p] = v;
    }
}

extern "C" void kernel_launch(void* const* d_in, const int* in_sizes, int n_in,
                              void* d_out, int out_size, void* d_ws, size_t ws_size,
                              hipStream_t stream) {
    const void* px  = d_in[0];  const void* pei = d_in[1];  const void* ppos = d_in[2];
    const void* pemb = d_in[3]; const void* pgW = d_in[4];  const void* pgB  = d_in[5];
    const void* pm1W = d_in[6]; const void* pm1B = d_in[7]; const void* pm2W = d_in[8];
    const void* pm2B = d_in[9]; const void* pm3W = d_in[10]; const void* pm3B = d_in[11];
    const void* plW = d_in[12]; const void* plB = d_in[13];
    {
        int c2048 = 0, c64 = 0, c32 = 0;
        for (int i = 0; i < n_in; i++) {
            int s = in_sizes[i]; const void* p = d_in[i];
            switch (s) {
                case 768:   px = p; break;
                case 49152: pei = p; break;
                case 8192:  ppos = p; break;
                case 3232:  pemb = p; break;
                case 2048:  if (c2048 == 0) pgW = p; else if (c2048 == 1) pm1W = p; else pm2W = p; c2048++; break;
                case 64:    if (c64 == 0) pgB = p; else plW = p; c64++; break;
                case 32:    if (c32 == 0) pm1B = p; else if (c32 == 1) pm2B = p; else pm3B = p; c32++; break;
                case 1056:  pm3W = p; break;
                case 1:     plB = p; break;
                default: break;
            }
        }
    }

    char* ws = (char*)d_ws;
    size_t off = 0;
    auto alloc = [&](size_t bytes) -> void* {
        void* pp = ws + off;
        off += (bytes + 255) & ~(size_t)255;
        return pp;
    };
    // ---- single contiguous zeroed region: cell + aux (one memset) ----
    int*   cell    = (int*)alloc(NCELL * 4);
    int*   rowlen  = (int*)alloc(NN * 4);
    int*   rtot    = (int*)alloc(NN * 4);
    int*   cursor  = (int*)alloc(NN * 4);
    float* stats   = (float*)alloc(NREP * 80 * 4);
    float* stats1  = (float*)alloc(NREP * 80 * 4);
    int*   dcs     = (int*)alloc(8 * 4);
    size_t zerolen = (ws + off) - (char*)cell;
    // ------------------------------------------------------
    int*   pcur    = (int*)alloc(NCELL * 4);
    int*   row_base= (int*)alloc(NN * 4);
    int*   row_ptr = (int*)alloc((NN + 1) * 4);
    int*   col_idx = (int*)alloc(NE * 4);
    float* cntv    = (float*)alloc(NE * 4);
    int*   pr_row  = (int*)alloc(NE * 4);
    float* dinv    = (float*)alloc(NN * 4);
    float* h       = (float*)alloc(NN * 32 * 4);
    float* bufA    = (float*)alloc(NN * 32 * 4);
    float* bufB    = (float*)alloc(NN * 32 * 4);
    bf16*  xep     = (bf16*)alloc(NE * 32 * 2);
    bf16*  mulp    = (bf16*)alloc(NE * 32 * 2);
    float* nrm     = (float*)alloc(64 * 4);
    float* gwf     = (float*)alloc(2048 * 4);
    float* gbf     = (float*)alloc(64 * 4);
    float* w1f     = (float*)alloc(2048 * 4);
    float* b1f     = (float*)alloc(32 * 4);
    float* w2f     = (float*)alloc(2048 * 4);
    float* b2f     = (float*)alloc(32 * 4);
    float* w3q     = (float*)alloc(32 * 36 * 4);
    float* linf    = (float*)alloc(64 * 4);
    float* linb    = (float*)alloc(4);
    int*   modeg   = (int*)alloc(4);
    size_t remain = (ws_size > off) ? (ws_size - off) : 0;
    int cap = (int)(remain / 8);
    if (cap > (1 << 20)) cap = (1 << 20);
    int2*  paths2  = (int2*)alloc((size_t)cap * 8);

    hipMemsetAsync(cell, 0, zerolen, stream);
    k_scatter<<<97, 256, 0, stream>>>((const int*)pei, cell, rowlen, row_ptr, dinv, &dcs[0],
                                      pgW, pgB, pm1W, pm1B, pm2W, pm2B, pm3W, pm3B, plW, plB,
                                      pemb, modeg, gwf, gbf, w1f, b1f, w2f, b2f, w3q, linf, linb);
    k_fill<<<NBLK + 96, 256, 0, stream>>>(cell, row_ptr, cursor, col_idx, cntv, pr_row,
                                          rowlen, rtot, (const int*)px, pemb, modeg, bufA);
    k_aggmw0<<<1 + NN, 256, 0, stream>>>(rtot, row_base, row_ptr, col_idx, bufA, dinv, gwf, gbf, bufB);
    k_hist<<<NN, 256, 0, stream>>>(row_ptr, col_idx, row_base, pcur, paths2, cap, bufB,
                                   dinv, gwf, gbf, bufA, stats1);
    k_emlp<<<3072 + 96, 256, 0, stream>>>(bufA, stats1, row_ptr, col_idx, pr_row, cntv,
                                          w1f, b1f, w2f, b2f, xep, mulp, h);
    k_big<<<NBIG, 256, 0, stream>>>(pcur, paths2, cell, xep, mulp,
                                    w3q, stats, &dcs[1], nrm, cap);
    k_out<<<NPOS / 4, 256, 0, stream>>>((const int*)ppos, pcur, paths2, cell, xep, mulp, h,
                                        w3q, nrm, linf, linb, modeg, cap, d_out);
}

// Round 17
// 278.147 us; speedup vs baseline: 1.7860x; 1.7860x over previous
//
#include <hip/hip_runtime.h>
#include <hip/hip_bf16.h>

#define NN 768
#define NE 24576
#define NPOS 4096
#define NCELL (NN*NN)   // 589824
#define NBLK 2304
#define NBIG 2304       // k_big: 256 cells/block, 1 cell/thread
#define BCELLS 256
#define CAP 4
#define NREP 16

typedef __hip_bfloat16 bf16;

__device__ __forceinline__ float ldf(const void* p, int i, int mode) {
    return mode ? __bfloat162float(((const bf16*)p)[i]) : ((const float*)p)[i];
}
__device__ __forceinline__ float aread(float* p) { return atomicAdd(p, 0.f); }
__device__ __forceinline__ int areadi(int* p) { return atomicAdd(p, 0); }

template<int D, int HALF>
__device__ __forceinline__ void redRound(float* v, int lane) {
#pragma unroll
    for (int i = 0; i < HALF; i++) {
        float snd = (lane & D) ? v[i] : v[i + HALF];
        float r = __shfl_xor(snd, D);
        v[i] = ((lane & D) ? v[i + HALF] : v[i]) + r;
    }
}

#define DOT4(Z, A, W) Z += A.x * W.x + A.y * W.y + A.z * W.z + A.w * W.w

// bf16 unpack helpers: uint = (bf16 even) | (bf16 odd << 16)
#define BLO(u) __uint_as_float((u) << 16)
#define BHI(u) __uint_as_float((u) & 0xFFFF0000u)

// bf16 gather: 8 independent 16B loads per path; unpack 2 bit-ops/value into fp32 accumulators.
#define GATHB(rec, q0,q1,q2,q3,q4,q5,q6,q7) { \
    const uint4* xr = xep4b + (int)((unsigned)(rec).x & 0x7FFFu) * 4; \
    const uint4* mr = mulp4b + (int)((unsigned)(rec).y & 0x7FFFu) * 4; \
    uint4 xA = xr[0], xB = xr[1], xC = xr[2], xD = xr[3]; \
    uint4 mA = mr[0], mB = mr[1], mC = mr[2], mD = mr[3]; \
    q0.x += BLO(xA.x)*BLO(mA.x); q0.y += BHI(xA.x)*BHI(mA.x); \
    q0.z += BLO(xA.y)*BLO(mA.y); q0.w += BHI(xA.y)*BHI(mA.y); \
    q1.x += BLO(xA.z)*BLO(mA.z); q1.y += BHI(xA.z)*BHI(mA.z); \
    q1.z += BLO(xA.w)*BLO(mA.w); q1.w += BHI(xA.w)*BHI(mA.w); \
    q2.x += BLO(xB.x)*BLO(mB.x); q2.y += BHI(xB.x)*BHI(mB.x); \
    q2.z += BLO(xB.y)*BLO(mB.y); q2.w += BHI(xB.y)*BHI(mB.y); \
    q3.x += BLO(xB.z)*BLO(mB.z); q3.y += BHI(xB.z)*BHI(mB.z); \
    q3.z += BLO(xB.w)*BLO(mB.w); q3.w += BHI(xB.w)*BHI(mB.w); \
    q4.x += BLO(xC.x)*BLO(mC.x); q4.y += BHI(xC.x)*BHI(mC.x); \
    q4.z += BLO(xC.y)*BLO(mC.y); q4.w += BHI(xC.y)*BHI(mC.y); \
    q5.x += BLO(xC.z)*BLO(mC.z); q5.y += BHI(xC.z)*BHI(mC.z); \
    q5.z += BLO(xC.w)*BLO(mC.w); q5.w += BHI(xC.w)*BHI(mC.w); \
    q6.x += BLO(xD.x)*BLO(mD.x); q6.y += BHI(xD.x)*BHI(mD.x); \
    q6.z += BLO(xD.y)*BLO(mD.y); q6.w += BHI(xD.y)*BHI(mD.y); \
    q7.x += BLO(xD.z)*BLO(mD.z); q7.y += BHI(xD.z)*BHI(mD.z); \
    q7.z += BLO(xD.w)*BLO(mD.w); q7.w += BHI(xD.w)*BHI(mD.w); }

// ---------------- edge scatter (b<96) || weight conv (b==96); last scatter block: row scan + dinv ----------------
__global__ void k_scatter(const int* __restrict__ ei, int* __restrict__ cell, int* __restrict__ rowlen,
                          int* __restrict__ row_ptr, float* __restrict__ dinv, int* __restrict__ dc,
                          const void* __restrict__ gW, const void* __restrict__ gB,
                          const void* __restrict__ m1W, const void* __restrict__ m1B,
                          const void* __restrict__ m2W, const void* __restrict__ m2B,
                          const void* __restrict__ m3W, const void* __restrict__ m3B,
                          const void* __restrict__ lW,  const void* __restrict__ lB,
                          const void* __restrict__ emb, int* __restrict__ modeg,
                          float* __restrict__ gwf, float* __restrict__ gbf,
                          float* __restrict__ w1f, float* __restrict__ b1f,
                          float* __restrict__ w2f, float* __restrict__ b2f,
                          float* __restrict__ w3q, float* __restrict__ linf, float* __restrict__ linb) {
    int t = threadIdx.x;
    if (blockIdx.x == 96) {
        __shared__ int bad;
        if (t == 0) bad = 0;
        __syncthreads();
        int local = 0;
        for (int i = t; i < 3232; i += 256) {
            float a = fabsf(__bfloat162float(((const bf16*)emb)[i]));
            if (!(a < 100.f)) local = 1;
        }
        if (local) atomicOr(&bad, 1);
        __syncthreads();
        int mode = bad ? 0 : 1;
        if (t == 0) *modeg = mode;
        for (int i = t; i < 2048; i += 256) {
            gwf[i] = ldf(gW, i, mode);
            w1f[i] = ldf(m1W, i, mode);
            w2f[i] = ldf(m2W, i, mode);
        }
        for (int i = t; i < 64; i += 256) { gbf[i] = ldf(gB, i, mode); linf[i] = ldf(lW, i, mode); }
        if (t < 32) { b1f[t] = ldf(m1B, t, mode); b2f[t] = ldf(m2B, t, mode); }
        // w3q row d (stride 36 floats, 16B-aligned): [W3[0..31][d], ind, b3, 0, 0]
        for (int i = t; i < 1056; i += 256) { int c = i >> 5, d = i & 31; w3q[d * 36 + c] = ldf(m3W, i, mode); }
        if (t < 32) { w3q[t * 36 + 33] = ldf(m3B, t, mode); w3q[t * 36 + 34] = 0.f; w3q[t * 36 + 35] = 0.f; }
        if (t == 0) linb[0] = ldf(lB, 0, mode);
        return;
    }
    __shared__ int amlast;
    __shared__ int sI[256];
    int e = blockIdx.x * 256 + t;
    int a = ei[e], b = ei[NE + e];
    if ((unsigned)a < (unsigned)NN && (unsigned)b < (unsigned)NN) {
        int old = atomicAdd(&cell[a * NN + b], 1);
        if (old == 0) atomicAdd(&rowlen[a], 1);
    }
    __syncthreads();
    if (t == 0) { __threadfence(); amlast = (atomicAdd(dc, 1) == 95) ? 1 : 0; }
    __syncthreads();
    if (!amlast) return;
    int i0 = 3 * t;
    int r0 = areadi(&rowlen[i0]), r1 = areadi(&rowlen[i0 + 1]), r2 = areadi(&rowlen[i0 + 2]);
    dinv[i0]     = rsqrtf((float)r0 + 1.f);
    dinv[i0 + 1] = rsqrtf((float)r1 + 1.f);
    dinv[i0 + 2] = rsqrtf((float)r2 + 1.f);
    int s3 = r0 + r1 + r2;
    sI[t] = s3;
    __syncthreads();
    for (int off = 1; off < 256; off <<= 1) {
        int tmp = (t >= off) ? sI[t - off] : 0;
        __syncthreads();
        sI[t] += tmp;
        __syncthreads();
    }
    int excl = sI[t] - s3;
    row_ptr[i0] = excl;
    row_ptr[i0 + 1] = excl + r0;
    row_ptr[i0 + 2] = excl + r0 + r1;
    if (t == 255) row_ptr[NN] = sI[255];
}

// ---------------- CSR fill + rtot (b<2304) || emb gather E -> bufA (b>=2304) ----------------
__global__ void k_fill(int* __restrict__ cell, const int* __restrict__ row_ptr, int* __restrict__ cursor,
                       int* __restrict__ col_idx, float* __restrict__ cntv, int* __restrict__ pr_row,
                       const int* __restrict__ rowlen, int* __restrict__ rtot,
                       const int* __restrict__ x, const void* __restrict__ emb,
                       const int* __restrict__ modep, float* __restrict__ bufA) {
    int t = threadIdx.x;
    int b = blockIdx.x;
    if (b < NBLK) {
        int idx = b * 256 + t;
        int i = idx / NN;
        int j = idx - i * NN;
        int cv = cell[idx];
        if (cv > 0) {
            int p = row_ptr[i] + atomicAdd(&cursor[i], 1);
            col_idx[p] = j; cntv[p] = (float)cv; pr_row[p] = i;
            cell[idx] = p;
            atomicAdd(&rtot[i], rowlen[j]);
        } else cell[idx] = -1;
    } else {
        int idx = (b - NBLK) * 256 + t;   // 768*32
        int i = idx >> 5, k = idx & 31;
        int xi = x[i]; if (xi < 0) xi = 0; if (xi > 100) xi = 100;
        bufA[idx] = ldf(emb, xi * 32 + k, *modep);
    }
}

// ---------------- b==0: row_base scan || b>=1: ROW-PER-BLOCK agg(E) then @W0 -> bufB ----------------
__global__ void k_aggmw0(const int* __restrict__ rtot, int* __restrict__ row_base,
                         const int* __restrict__ row_ptr, const int* __restrict__ col_idx,
                         const float* __restrict__ bufA, const float* __restrict__ dinv,
                         const float* __restrict__ gwf, const float* __restrict__ gbf,
                         float* __restrict__ bufB) {
    int t = threadIdx.x;
    if (blockIdx.x == 0) {
        __shared__ int sI[256];
        int r3[3]; int s3 = 0;
#pragma unroll
        for (int q = 0; q < 3; q++) { r3[q] = rtot[3 * t + q]; s3 += r3[q]; }
        sI[t] = s3;
        __syncthreads();
        for (int off = 1; off < 256; off <<= 1) {
            int tmp = (t >= off) ? sI[t - off] : 0;
            __syncthreads();
            sI[t] += tmp;
            __syncthreads();
        }
        int run = sI[t] - s3;
        row_base[3 * t] = run;
        row_base[3 * t + 1] = run + r3[0];
        row_base[3 * t + 2] = run + r3[0] + r3[1];
        return;
    }
    __shared__ float sg8[8][32];
    __shared__ float agg[32];
    int sgi = t >> 5, k = t & 31;
    int i = blockIdx.x - 1;
    int base = row_ptr[i], len = row_ptr[i + 1] - base;
    float di = dinv[i];
    float acc = (sgi == 0) ? di * bufA[i * 32 + k] : 0.f;
    for (int e = sgi; e < len; e += 8) {
        int c = col_idx[base + e];
        acc += dinv[c] * bufA[c * 32 + k];
    }
    sg8[sgi][k] = acc;
    __syncthreads();
    if (t < 32) {
        float s = 0.f;
#pragma unroll
        for (int q = 0; q < 8; q++) s += sg8[q][k];
        agg[k] = di * s;
    }
    __syncthreads();
    if (t < 32) {
        int d = k;
        float s = gbf[d];
#pragma unroll
        for (int kk = 0; kk < 32; kk++) s += agg[kk] * gwf[kk * 32 + d];
        bufB[i * 32 + d] = s;
    }
}

// ---------------- per-row path histogram (b<768) || nrm0 from bufB (b==768) ----------------
__global__ void k_hist(const int* __restrict__ row_ptr, const int* __restrict__ col_idx,
                       const int* __restrict__ row_base,
                       int* __restrict__ pcur, int2* __restrict__ paths2, int cap,
                       const float* __restrict__ bufB, float* __restrict__ nrm0) {
    int t = threadIdx.x;
    if (blockIdx.x == NN) {
        __shared__ float r1[256], r2[256];
        int dd = t & 31, g = t >> 5;
        float s = 0.f, s2 = 0.f;
        for (int r = g; r < NN; r += 8) { float v = bufB[r * 32 + dd]; s += v; s2 += v * v; }
        r1[t] = s; r2[t] = s2;
        __syncthreads();
        if (t < 32) {
            float a = 0.f, b2 = 0.f;
            for (int k = 0; k < 8; k++) { a += r1[k * 32 + t]; b2 += r2[k * 32 + t]; }
            float mean = a / (float)NN;
            float var = b2 / (float)NN - mean * mean;
            nrm0[t] = mean;
            nrm0[32 + t] = rsqrtf(fmaxf(var, 0.f) + 1e-5f);
        }
        return;
    }
    __shared__ int hist[NN];
    __shared__ int sc[256];
    int i = blockIdx.x;
    int base = row_ptr[i], len = row_ptr[i + 1] - base;
    int rb = row_base[i];
    int wave = t >> 6, lane = t & 63;
    int sub = lane >> 5, l2 = lane & 31;
    for (int j = t; j < NN; j += 256) hist[j] = 0;
    __syncthreads();
    for (int ee = wave * 2 + sub; ee < len; ee += 8) {
        int k = col_idx[base + ee];
        int kb = row_ptr[k], ke = row_ptr[k + 1];
        for (int e = kb + l2; e < ke; e += 32) atomicAdd(&hist[col_idx[e]], 1);
    }
    __syncthreads();
    int h0 = hist[3 * t], h1 = hist[3 * t + 1], h2 = hist[3 * t + 2];
    int s3 = h0 + h1 + h2;
    sc[t] = s3;
    __syncthreads();
    for (int off = 1; off < 256; off <<= 1) {
        int tmp = (t >= off) ? sc[t - off] : 0;
        __syncthreads();
        sc[t] += tmp;
        __syncthreads();
    }
    int excl = sc[t] - s3;
    int n0 = i * NN + 3 * t;
    pcur[n0]     = rb + excl + h0;            // absolute END offsets
    pcur[n0 + 1] = rb + excl + h0 + h1;
    pcur[n0 + 2] = rb + excl + h0 + h1 + h2;
    hist[3 * t] = excl;
    hist[3 * t + 1] = excl + h0;
    hist[3 * t + 2] = excl + h0 + h1;
    __syncthreads();
    for (int ee = wave * 2 + sub; ee < len; ee += 8) {
        int e1 = base + ee;
        int k = col_idx[e1];
        int kb = row_ptr[k], ke = row_ptr[k + 1];
        for (int e = kb + l2; e < ke; e += 32) {
            int j = col_idx[e];
            int slot = rb + atomicAdd(&hist[j], 1);
            if (slot < cap) {
                // pack cell id n (20 bits) into high bits: x[31:15]=n[16:0], y[17:15]=n[19:17]
                unsigned n2 = (unsigned)(i * NN + j);
                paths2[slot] = make_int2((int)((unsigned)e1 | ((n2 & 0x1FFFFu) << 15)),
                                         (int)((unsigned)e  | ((n2 >> 17) << 15)));
            }
        }
    }
}

// ---------------- ROW-PER-BLOCK agg(g(bufB,nrm0)) then @W1 -> bufA ; stats1 partials ----------------
__global__ void k_aggmw1(const int* __restrict__ row_ptr, const int* __restrict__ col_idx,
                         const float* __restrict__ bufB, const float* __restrict__ nrm0,
                         const float* __restrict__ dinv,
                         const float* __restrict__ gwf, const float* __restrict__ gbf,
                         float* __restrict__ bufA, float* __restrict__ stats1) {
    __shared__ float sg8[8][32];
    __shared__ float agg[32];
    int t = threadIdx.x;
    int sgi = t >> 5, k = t & 31;
    int i = blockIdx.x;
    float mk = nrm0[k], rk = nrm0[32 + k];
    int base = row_ptr[i], len = row_ptr[i + 1] - base;
    float di = dinv[i];
    float acc = (sgi == 0) ? di * fmaxf((bufB[i * 32 + k] - mk) * rk, 0.f) : 0.f;
    for (int e = sgi; e < len; e += 8) {
        int c = col_idx[base + e];
        acc += dinv[c] * fmaxf((bufB[c * 32 + k] - mk) * rk, 0.f);
    }
    sg8[sgi][k] = acc;
    __syncthreads();
    if (t < 32) {
        float s = 0.f;
#pragma unroll
        for (int q = 0; q < 8; q++) s += sg8[q][k];
        agg[k] = di * s;
    }
    __syncthreads();
    if (t < 32) {
        int d = k;
        const float* W = gwf + 1024;
        float s = gbf[32 + d];
#pragma unroll
        for (int kk = 0; kk < 32; kk++) s += agg[kk] * W[kk * 32 + d];
        bufA[i * 32 + d] = s;
        float* rep = stats1 + (blockIdx.x & (NREP - 1)) * 80;
        atomicAdd(&rep[d], s);
        atomicAdd(&rep[32 + d], s * s);
    }
}

// ---------------- edge MLP (b<3072) || h write (b>=3072); nrm1 computed locally; xep/mulp bf16 ----------------
__global__ void k_emlp(const float* __restrict__ bufA, const float* __restrict__ stats1,
                       const int* __restrict__ row_ptr, const int* __restrict__ col_idx,
                       const int* __restrict__ pr_row, const float* __restrict__ cntv,
                       const float* __restrict__ w1f, const float* __restrict__ b1f,
                       const float* __restrict__ w2f, const float* __restrict__ b2f,
                       bf16* __restrict__ xepb, bf16* __restrict__ mulpb, float* __restrict__ h) {
    __shared__ float nmean[32], nrstd[32];
    int t = threadIdx.x;
    int b = blockIdx.x;
    if (t < 32) {
        float s = 0.f, s2 = 0.f;
#pragma unroll
        for (int r = 0; r < NREP; r++) { s += stats1[r * 80 + t]; s2 += stats1[r * 80 + 32 + t]; }
        float mean = s / (float)NN;
        float var = s2 / (float)NN - mean * mean;
        nmean[t] = mean;
        nrstd[t] = rsqrtf(fmaxf(var, 0.f) + 1e-5f);
    }
    __syncthreads();
    if (b < 3072) {
        int d = t & 31;
        int p = b * 8 + (t >> 5);
        if (p >= row_ptr[NN]) {
            if (p < NE) { xepb[p * 32 + d] = __float2bfloat16(0.f); mulpb[p * 32 + d] = __float2bfloat16(0.f); }
            return;
        }
        int i = pr_row[p], j = col_idx[p];
        float a1 = b1f[d], a2 = b2f[d];
#pragma unroll
        for (int c = 0; c < 32; c++) {
            float hv = fmaxf((bufA[i * 32 + c] - nmean[c]) * nrstd[c], 0.f);
            a1 += hv * w1f[c * 32 + d];
            a2 += hv * w2f[c * 32 + d];
        }
#pragma unroll
        for (int c = 0; c < 32; c++) {
            float hv = fmaxf((bufA[j * 32 + c] - nmean[c]) * nrstd[c], 0.f);
            a1 += hv * w1f[(32 + c) * 32 + d];
            a2 += hv * w2f[(32 + c) * 32 + d];
        }
        float cv = cntv[p];
        xepb[p * 32 + d]  = __float2bfloat16(cv * fmaxf(a1, 0.f));
        mulpb[p * 32 + d] = __float2bfloat16(cv * fmaxf(a2, 0.f));
    } else {
        int idx = (b - 3072) * 256 + t;
        int d = idx & 31;
        h[idx] = fmaxf((bufA[idx] - nmean[d]) * nrstd[d], 0.f);
    }
}

// ---------------- fused big: v12/v9 config ((256,4) spill-free, ~91us) -- BEST MEASURED ----------------
// All launch_bounds >4 waves/EU spill ((256,8)->32VGPR/292MB, (256,6)->40/17MB, (128,6)->40/18MB,
// halved-accumulator (256,8)->32/292MB). k_big is latency-bound on ~2 serial L2-hit chains/thread
// at the 2.6 waves/SIMD that the spill-free register class permits; bytes (bf16), transactions
// (LDS x-cache), and scheduling (batched prefetch) are all confirmed off the critical path.
__global__ __launch_bounds__(256, 4) void k_big(const int* __restrict__ pcur,
                                                const int2* __restrict__ paths2,
                                                const int* __restrict__ cellA,
                                                const bf16* __restrict__ xepb, const bf16* __restrict__ mulpb,
                                                const float* __restrict__ w3q,
                                                float* __restrict__ stats, int* __restrict__ done,
                                                float* __restrict__ nrm, int cap) {
    __shared__ float qbuf[64 * 32];
    __shared__ int qps[64], qpe[64];
    __shared__ float sS1[32], sS2[32];
    __shared__ float sCm;
    __shared__ int amlast;
    __shared__ int qcnt;
    const uint4* xep4b = (const uint4*)xepb;
    const uint4* mulp4b = (const uint4*)mulpb;
    int t = threadIdx.x;
    int b = blockIdx.x;
    int cell0 = b * BCELLS;
    int wid = t >> 6, lane = t & 63, half = lane >> 5, d = lane & 31;

    if (t == 0) { sCm = 0.f; qcnt = 0; }
    if (t < 32) { sS1[t] = 0.f; sS2[t] = 0.f; }
    // per-thread cell meta (coalesced)
    int myn = cell0 + t;
    int mp1 = pcur[myn];
    int mp0 = (myn == 0) ? 0 : pcur[myn - 1];
    int madj = cellA[myn];
    if (mp0 > cap) mp0 = cap;
    if (mp1 > cap) mp1 = cap;
    __syncthreads();   // qcnt init visible before pushes

    // ---- stage 1a: per-thread register gather; all recs prefetched; capped at CAP paths ----
    int len = mp1 - mp0;
    int take = (len > CAP) ? CAP : len;
    int myq = -1;
    if (len > CAP) {
        int s = atomicAdd(&qcnt, 1);
        if (s < 64) { myq = s; qps[s] = mp0 + CAP; qpe[s] = mp1; }
    }
    int pm = cap - 1; if (pm < 0) pm = 0;
    int i0 = mp0, i1 = mp0 + 1, i2 = mp0 + 2, i3 = mp0 + 3;
    if (i0 > pm) i0 = pm; if (i1 > pm) i1 = pm; if (i2 > pm) i2 = pm; if (i3 > pm) i3 = pm;
    // 4 independent rec loads issued back-to-back (clamped: always valid)
    int2 r0 = paths2[i0];
    int2 r1 = paths2[i1];
    int2 r2 = paths2[i2];
    int2 r3 = paths2[i3];
    float4 q0 = {0.f,0.f,0.f,0.f}, q1 = q0, q2 = q0, q3 = q0, q4 = q0, q5 = q0, q6 = q0, q7 = q0;
    if (take > 0) GATHB(r0, q0, q1, q2, q3, q4, q5, q6, q7);
    if (take > 1) GATHB(r1, q0, q1, q2, q3, q4, q5, q6, q7);
    if (take > 2) GATHB(r2, q0, q1, q2, q3, q4, q5, q6, q7);
    if (take > 3) GATHB(r3, q0, q1, q2, q3, q4, q5, q6, q7);
    __syncthreads();   // queue pushes visible

    // ---- stage 1b: heavy-cell remainders, wave-parallel (lanes = 2 path-slots x 32d) ----
    int nq = qcnt; if (nq > 64) nq = 64;
    for (int e = wid; e < nq; e += 4) {
        int pe = qpe[e];
        float acc = 0.f;
        for (int q = qps[e] + half; q < pe; q += 2) {
            int2 r = paths2[q];
            acc += __bfloat162float(xepb[(int)((unsigned)r.x & 0x7FFFu) * 32 + d]) *
                   __bfloat162float(mulpb[(int)((unsigned)r.y & 0x7FFFu) * 32 + d]);
        }
        acc += __shfl_xor(acc, 32);
        if (lane < 32) qbuf[e * 32 + lane] = acc;
    }
    __syncthreads();
    if (myq >= 0) {   // merge remainder into registers (rare: ~3 threads/block)
        const float4* qb = (const float4*)(qbuf + myq * 32);
        float4 a0 = qb[0], a1 = qb[1], a2 = qb[2], a3 = qb[3];
        float4 a4 = qb[4], a5 = qb[5], a6 = qb[6], a7 = qb[7];
        q0.x += a0.x; q0.y += a0.y; q0.z += a0.z; q0.w += a0.w;
        q1.x += a1.x; q1.y += a1.y; q1.z += a1.z; q1.w += a1.w;
        q2.x += a2.x; q2.y += a2.y; q2.z += a2.z; q2.w += a2.w;
        q3.x += a3.x; q3.y += a3.y; q3.z += a3.z; q3.w += a3.w;
        q4.x += a4.x; q4.y += a4.y; q4.z += a4.z; q4.w += a4.w;
        q5.x += a5.x; q5.y += a5.y; q5.z += a5.z; q5.w += a5.w;
        q6.x += a6.x; q6.y += a6.y; q6.z += a6.z; q6.w += a6.w;
        q7.x += a7.x; q7.y += a7.y; q7.z += a7.z; q7.w += a7.w;
    }

    // ---- stage 2: thread t owns cell (cell0+t); register z matvec + masked stats ----
    float af = (madj >= 0) ? 1.f : 0.f;
    float msk = (len > 0 || madj >= 0) ? 1.f : 0.f;
#pragma unroll
    for (int ch = 0; ch < 2; ch++) {
        float v[32];
#pragma unroll
        for (int j = 0; j < 16; j++) {
            int dd = ch * 16 + j;
            const float4* wr = (const float4*)(w3q + dd * 36);   // wave-uniform -> s_load
            float4 wv = wr[8];
            float za = wv.y + af * wv.x;
            wv = wr[0]; DOT4(za, q0, wv);
            wv = wr[1]; DOT4(za, q1, wv);
            wv = wr[2]; DOT4(za, q2, wv);
            wv = wr[3]; DOT4(za, q3, wv);
            wv = wr[4]; DOT4(za, q4, wv);
            wv = wr[5]; DOT4(za, q5, wv);
            wv = wr[6]; DOT4(za, q6, wv);
            wv = wr[7]; DOT4(za, q7, wv);
            v[j] = msk * za;
            v[16 + j] = msk * za * za;
        }
#pragma unroll
        for (int i2r = 0; i2r < 32; i2r++) v[i2r] += __shfl_xor(v[i2r], 32);
        redRound<16, 16>(v, lane);
        redRound<8, 8>(v, lane);
        redRound<4, 4>(v, lane);
        redRound<2, 2>(v, lane);
        redRound<1, 1>(v, lane);
        if (lane < 32) {
            if (lane < 16) atomicAdd(&sS1[ch * 16 + lane], v[0]);
            else           atomicAdd(&sS2[ch * 16 + lane - 16], v[0]);
        }
    }
    {
        float cm2 = msk;
        for (int off = 32; off >= 1; off >>= 1) cm2 += __shfl_xor(cm2, off);
        if (lane == 0) atomicAdd(&sCm, cm2);
    }
    __syncthreads();
    float* srep = stats + (b & (NREP - 1)) * 80;
    if (t < 32) {
        atomicAdd(&srep[t], sS1[t]);
        atomicAdd(&srep[32 + t], sS2[t]);
    }
    if (t == 32) atomicAdd(&srep[64], sCm);
    __syncthreads();
    if (t == 0) {
        __threadfence();
        amlast = (atomicAdd(done, 1) == NBIG - 1) ? 1 : 0;
    }
    __syncthreads();
    if (amlast && t < 32) {
        float sum1 = 0.f, sum2 = 0.f;
        for (int r = 0; r < NREP; r++) {
            sum1 += aread(&stats[r * 80 + t]);
            sum2 += aread(&stats[r * 80 + 32 + t]);
        }
        float cmt = 0.f;
        for (int r = 0; r < NREP; r++) cmt += aread(&stats[r * 80 + 64]);
        if (cmt < 1.f) cmt = 1.f;
        float mean = sum1 / cmt;
        float var = sum2 / cmt - mean * mean;
        nrm[t] = mean;
        nrm[32 + t] = rsqrtf(fmaxf(var, 0.f) + 1e-5f);
    }
}

// ---------------- output: C at pos pairs via path lists, norm, sym, linear (bf16 gathers) ----------------
__global__ void k_out(const int* __restrict__ pos, const int* __restrict__ pcur,
                      const int2* __restrict__ paths2,
                      const int* __restrict__ cell,
                      const bf16* __restrict__ xepb, const bf16* __restrict__ mulpb,
                      const float* __restrict__ h,
                      const float* __restrict__ w3q,
                      const float* __restrict__ nrm,
                      const float* __restrict__ linf, const float* __restrict__ linb,
                      const int* __restrict__ modep, int cap, void* __restrict__ outp) {
    __shared__ float Cb[4][2][32];
    int t = threadIdx.x;
    int w = t >> 6, lane = t & 63, d = lane & 31, dir = lane >> 5;
    int p = blockIdx.x * 4 + w;
    int a = pos[2 * p], b = pos[2 * p + 1];
    if ((unsigned)a >= (unsigned)NN) a = 0;
    if ((unsigned)b >= (unsigned)NN) b = 0;
    int r = dir ? b : a;
    int cc = dir ? a : b;
    int n = r * NN + cc;
    int p1 = pcur[n];
    int p0 = (n == 0) ? 0 : pcur[n - 1];
    if (p0 > cap) p0 = cap; if (p1 > cap) p1 = cap;
    float acc = 0.f;
    for (int q = p0; q < p1; q++) {
        int2 rec = paths2[q];
        int e1 = (int)((unsigned)rec.x & 0x7FFFu);
        int e2 = (int)((unsigned)rec.y & 0x7FFFu);
        acc += __bfloat162float(xepb[e1 * 32 + d]) * __bfloat162float(mulpb[e2 * 32 + d]);
    }
    Cb[w][dir][d] = acc;
    bool adj = cell[n] >= 0;
    float msk = (p1 > p0 || adj) ? 1.f : 0.f;
    __syncthreads();
    float z = w3q[d * 36 + 33] + (adj ? 1.f : 0.f) * w3q[d * 36 + 32];
#pragma unroll
    for (int c = 0; c < 32; c++) z += Cb[w][dir][c] * w3q[d * 36 + c];
    float zn = fmaxf((z - nrm[d]) * nrm[32 + d], 0.f);
    float zp = __shfl_xor(zn, 32);
    float symd = msk * zn * zp;
    float xxd = h[a * 32 + d] * h[b * 32 + d];
    float contrib = symd * linf[d] + xxd * linf[32 + d];
    for (int off = 16; off >= 1; off >>= 1) contrib += __shfl_xor(contrib, off);
    if (lane == 0) {
        float v = contrib + linb[0];
        v = fminf(fmaxf(v, -1e4f), 1e4f);
        if (*modep) ((bf16*)outp)[p] = __float2bfloat16(v);
        else        ((float*)outp)[p] = v;
    }
}

extern "C" void kernel_launch(void* const* d_in, const int* in_sizes, int n_in,
                              void* d_out, int out_size, void* d_ws, size_t ws_size,
                              hipStream_t stream) {
    const void* px  = d_in[0];  const void* pei = d_in[1];  const void* ppos = d_in[2];
    const void* pemb = d_in[3]; const void* pgW = d_in[4];  const void* pgB  = d_in[5];
    const void* pm1W = d_in[6]; const void* pm1B = d_in[7]; const void* pm2W = d_in[8];
    const void* pm2B = d_in[9]; const void* pm3W = d_in[10]; const void* pm3B = d_in[11];
    const void* plW = d_in[12]; const void* plB = d_in[13];
    {
        int c2048 = 0, c64 = 0, c32 = 0;
        for (int i = 0; i < n_in; i++) {
            int s = in_sizes[i]; const void* p = d_in[i];
            switch (s) {
                case 768:   px = p; break;
                case 49152: pei = p; break;
                case 8192:  ppos = p; break;
                case 3232:  pemb = p; break;
                case 2048:  if (c2048 == 0) pgW = p; else if (c2048 == 1) pm1W = p; else pm2W = p; c2048++; break;
                case 64:    if (c64 == 0) pgB = p; else plW = p; c64++; break;
                case 32:    if (c32 == 0) pm1B = p; else if (c32 == 1) pm2B = p; else pm3B = p; c32++; break;
                case 1056:  pm3W = p; break;
                case 1:     plB = p; break;
                default: break;
            }
        }
    }

    char* ws = (char*)d_ws;
    size_t off = 0;
    auto alloc = [&](size_t bytes) -> void* {
        void* pp = ws + off;
        off += (bytes + 255) & ~(size_t)255;
        return pp;
    };
    int*   cell    = (int*)alloc(NCELL * 4);
    int*   pcur    = (int*)alloc(NCELL * 4);
    // ---- contiguous aux region (zeroed by one memset) ----
    char*  aux0    = ws + off;
    int*   rowlen  = (int*)alloc(NN * 4);
    int*   rtot    = (int*)alloc(NN * 4);
    int*   cursor  = (int*)alloc(NN * 4);
    float* stats   = (float*)alloc(NREP * 80 * 4);
    float* stats1  = (float*)alloc(NREP * 80 * 4);
    int*   dcs     = (int*)alloc(8 * 4);
    size_t auxlen  = (ws + off) - aux0;
    // ------------------------------------------------------
    int*   row_base= (int*)alloc(NN * 4);
    int*   row_ptr = (int*)alloc((NN + 1) * 4);
    int*   col_idx = (int*)alloc(NE * 4);
    float* cntv    = (float*)alloc(NE * 4);
    int*   pr_row  = (int*)alloc(NE * 4);
    float* dinv    = (float*)alloc(NN * 4);
    float* h       = (float*)alloc(NN * 32 * 4);
    float* bufA    = (float*)alloc(NN * 32 * 4);
    float* bufB    = (float*)alloc(NN * 32 * 4);
    bf16*  xep     = (bf16*)alloc(NE * 32 * 2);
    bf16*  mulp    = (bf16*)alloc(NE * 32 * 2);
    float* nrm     = (float*)alloc(64 * 4);
    float* nrm0    = (float*)alloc(64 * 4);
    float* gwf     = (float*)alloc(2048 * 4);
    float* gbf     = (float*)alloc(64 * 4);
    float* w1f     = (float*)alloc(2048 * 4);
    float* b1f     = (float*)alloc(32 * 4);
    float* w2f     = (float*)alloc(2048 * 4);
    float* b2f     = (float*)alloc(32 * 4);
    float* w3q     = (float*)alloc(32 * 36 * 4);
    float* linf    = (float*)alloc(64 * 4);
    float* linb    = (float*)alloc(4);
    int*   modeg   = (int*)alloc(4);
    size_t remain = (ws_size > off) ? (ws_size - off) : 0;
    int cap = (int)(remain / 8);
    if (cap > (1 << 20)) cap = (1 << 20);
    int2*  paths2  = (int2*)alloc((size_t)cap * 8);

    hipMemsetAsync(cell, 0, (size_t)NCELL * 4, stream);
    hipMemsetAsync(aux0, 0, auxlen, stream);
    k_scatter<<<97, 256, 0, stream>>>((const int*)pei, cell, rowlen, row_ptr, dinv, &dcs[0],
                                      pgW, pgB, pm1W, pm1B, pm2W, pm2B, pm3W, pm3B, plW, plB,
                                      pemb, modeg, gwf, gbf, w1f, b1f, w2f, b2f, w3q, linf, linb);
    k_fill<<<NBLK + 96, 256, 0, stream>>>(cell, row_ptr, cursor, col_idx, cntv, pr_row,
                                          rowlen, rtot, (const int*)px, pemb, modeg, bufA);
    k_aggmw0<<<1 + NN, 256, 0, stream>>>(rtot, row_base, row_ptr, col_idx, bufA, dinv, gwf, gbf, bufB);
    k_hist<<<NN + 1, 256, 0, stream>>>(row_ptr, col_idx, row_base, pcur, paths2, cap, bufB, nrm0);
    k_aggmw1<<<NN, 256, 0, stream>>>(row_ptr, col_idx, bufB, nrm0, dinv, gwf, gbf, bufA, stats1);
    k_emlp<<<3072 + 96, 256, 0, stream>>>(bufA, stats1, row_ptr, col_idx, pr_row, cntv,
                                          w1f, b1f, w2f, b2f, xep, mulp, h);
    k_big<<<NBIG, 256, 0, stream>>>(pcur, paths2, cell, xep, mulp,
                                    w3q, stats, &dcs[1], nrm, cap);
    k_out<<<NPOS / 4, 256, 0, stream>>>((const int*)ppos, pcur, paths2, cell, xep, mulp, h,
                                        w3q, nrm, linf, linb, modeg, cap, d_out);
}